// Round 9
// baseline (37.272 us; speedup 1.0000x reference)
//
#include <hip/hip_runtime.h>

#define HOP     256
#define WD      32
#define NFRM    4096
#define TLEN    1048832        // FRAMELEN + HOP*(NFRM-1)
#define LROW    786688         // 448 + 4095*192
#define XSTR    484            // x floats per frame (121 quads; 484 % 32 == 4)
#define DSTR    420            // g floats per chain (105 quads; 420 % 32 == 4)
#define XQn     121
#define DQn     105
#define XWAVE   984            // per-wave x region: 2*XSTR + 16 guard
#define GWAVE   1688           // per-wave g region: 4*DSTR + 8 guard

// 16-lane xor-butterfly sum within each row of 16; result in all 16 lanes.
__device__ __forceinline__ float red16(float v) {
    v += __int_as_float(__builtin_amdgcn_update_dpp(0, __float_as_int(v), 0xB1,  0xF, 0xF, true)); // xor1
    v += __int_as_float(__builtin_amdgcn_update_dpp(0, __float_as_int(v), 0x4E,  0xF, 0xF, true)); // xor2
    v += __int_as_float(__builtin_amdgcn_update_dpp(0, __float_as_int(v), 0x141, 0xF, 0xF, true)); // half-mirror
    v += __int_as_float(__builtin_amdgcn_update_dpp(0, __float_as_int(v), 0x140, 0xF, 0xF, true)); // row-mirror
    return v;
}

#define CL(v) __builtin_amdgcn_fmed3f((v), -65535.0f, 65535.0f)

// One LMS step. GV = 0.05*d (pre-scaled). gm = fmaf(-0.05, s, GV) = 0.05*e.
#define STEP1(Xa,Xb,Xc,Xd, GV, IND) do {                          \
    float p = w0 * (Xa);                                          \
    p = fmaf(w1, (Xb), p);                                        \
    p = fmaf(w2, (Xc), p);                                        \
    p = fmaf(w3, (Xd), p);                                        \
    float s  = red16(p);                                          \
    so = fmaf((IND), s, so);                                      \
    float gm = fmaf(-0.05f, s, (GV));                             \
    w0 = CL(fmaf(gm, (Xa), w0));                                  \
    w1 = CL(fmaf(gm, (Xb), w1));                                  \
    w2 = CL(fmaf(gm, (Xc), w2));                                  \
    w3 = CL(fmaf(gm, (Xd), w3));                                  \
} while (0)

#define GROUP4(QA, QB, GQ, Ia, Ib, Ic, Id) do {                   \
    STEP1(QA.x,QA.y,QA.z,QA.w, GQ.x, Ia);                         \
    STEP1(QA.y,QA.z,QA.w,QB.x, GQ.y, Ib);                         \
    STEP1(QA.z,QA.w,QB.x,QB.y, GQ.z, Ic);                         \
    STEP1(QA.w,QB.x,QB.y,QB.z, GQ.w, Id);                         \
} while (0)

// block = 128 threads = 2 waves; each wave owns 4 chains (L=16) and a
// PRIVATE LDS region it stages itself -> NO __syncthreads anywhere, so the
// two waves on a SIMD keep their natural phase offset for all 416 steps.
// Odd waves run at s_setprio(1): asymmetric arbitration breaks lockstep.
__global__ void __launch_bounds__(128, 2)
lms_kernel(const float* __restrict__ dmat, const float* __restrict__ xvec,
           float* __restrict__ out)
{
    __shared__ __align__(16) float lx[2 * XWAVE];
    __shared__ __align__(16) float lg[2 * GWAVE];

    const int tid  = threadIdx.x;
    const int lane = tid & 63;
    const int wv   = tid >> 6;                 // 0..1
    const int f0w  = blockIdx.x * 4 + wv * 2;  // this wave's first frame

    float* __restrict__ lxw = lx + wv * XWAVE;
    float* __restrict__ lgw = lg + wv * GWAVE;

    // ---- per-wave stage: 242 x-quads + 420 g-quads (0.05*d) ----
    for (int i = lane; i < 242 + 420; i += 64) {
        if (i < 242) {
            int fr = (i >= XQn) ? 1 : 0;
            int k  = i - fr * XQn;
            ((float4*)lxw)[i] =
                *(const float4*)(xvec + (size_t)(f0w + fr) * HOP + 4 * k);
        } else {
            int j   = i - 242;
            int idx = j / DQn, k = j - idx * DQn;   // idx = b*2 + r
            int b = idx >> 1, r = idx & 1;
            float4 v = *(const float4*)(dmat + (size_t)b * TLEN
                                        + (size_t)(f0w + r) * HOP + WD + 4 * k);
            float4 g2;
            g2.x = 0.05f * v.x; g2.y = 0.05f * v.y;
            g2.z = 0.05f * v.z; g2.w = 0.05f * v.w;
            ((float4*)lgw)[j] = g2;
        }
    }

    const int row  = lane >> 4;            // 0..3
    const int col  = lane & 15;            // taps 4*col .. 4*col+3
    const int fl   = row >> 1;             // local frame 0..1 within wave
    const int b    = row & 1;              // batch
    const int f    = f0w + fl;             // global frame
    const bool early = (f == 0);
    const int ci   = b * 2 + fl;           // chain slot in lgw

    const float4* __restrict__ xq  = (const float4*)(lxw + fl * XSTR + 4 * col);
    const float4* __restrict__ gq  = (const float4*)(lgw + ci * DSTR);
    const float*  __restrict__ lgs = lgw + ci * DSTR;

    float* od = out + (size_t)b * LROW + 32 + (size_t)192 * f;
    float* oe = od + 2 * (size_t)LROW;

    // leading 32 zeros of the 4 output rows
    if (blockIdx.x == 0) {
        out[(size_t)(tid >> 5) * LROW + (tid & 31)] = 0.0f;
    }

    // per-lane step indicators (statically indexed -> registers)
    const float i0  = (col ==  0) ? 1.f : 0.f, i1  = (col ==  1) ? 1.f : 0.f;
    const float i2  = (col ==  2) ? 1.f : 0.f, i3  = (col ==  3) ? 1.f : 0.f;
    const float i4  = (col ==  4) ? 1.f : 0.f, i5  = (col ==  5) ? 1.f : 0.f;
    const float i6  = (col ==  6) ? 1.f : 0.f, i7  = (col ==  7) ? 1.f : 0.f;
    const float i8  = (col ==  8) ? 1.f : 0.f, i9  = (col ==  9) ? 1.f : 0.f;
    const float i10 = (col == 10) ? 1.f : 0.f, i11 = (col == 11) ? 1.f : 0.f;
    const float i12 = (col == 12) ? 1.f : 0.f, i13 = (col == 13) ? 1.f : 0.f;
    const float i14 = (col == 14) ? 1.f : 0.f, i15 = (col == 15) ? 1.f : 0.f;

    float w0 = 0.f, w1 = 0.f, w2 = 0.f, w3 = 0.f;

    // asymmetric wave priority: one high, one low per SIMD pair
    if (wv & 1) __builtin_amdgcn_s_setprio(1);

    // prologue: 2-group lead
    float4 X0 = xq[0], X1 = xq[1], X2 = xq[2];
    float4 G0 = gq[0], G1 = gq[1];

    for (int j = 0; j < 26; ++j) {
        const int g = 4 * j;
        float so  = 0.f;
        float gvs = lgs[16 * j + col];             // for the store-time gm

        float4 X3 = xq[g+3];  float4 G2 = gq[g+2];
        GROUP4(X0, X1, G0, i0,  i1,  i2,  i3);

        X0 = xq[g+4];         float4 G3 = gq[g+3];
        GROUP4(X1, X2, G1, i4,  i5,  i6,  i7);

        X1 = xq[g+5];         G0 = gq[g+4];
        GROUP4(X2, X3, G2, i8,  i9,  i10, i11);

        X2 = xq[g+6];         G1 = gq[g+5];
        GROUP4(X3, X0, G3, i12, i13, i14, i15);

        if (j >= 14 || early) {
            float gms = fmaf(-0.05f, so, gvs);     // == in-loop gm bitwise
            od[16 * j + col] = so;                 // d_est
            oe[16 * j + col] = 20.0f * gms;        // e = 20 * (0.05*e)
        }
    }
}

extern "C" void kernel_launch(void* const* d_in, const int* in_sizes, int n_in,
                              void* d_out, int out_size, void* d_ws, size_t ws_size,
                              hipStream_t stream) {
    const float* dmat = (const float*)d_in[0];   // (2, TLEN)
    const float* xvec = (const float*)d_in[1];   // (TLEN,)
    float* out = (float*)d_out;                  // [d_est(2,LROW), e(2,LROW)]

    hipLaunchKernelGGL(lms_kernel, dim3(NFRM / 4), dim3(128), 0, stream,
                       dmat, xvec, out);
}